// Round 5
// baseline (578.329 us; speedup 1.0000x reference)
//
#include <hip/hip_runtime.h>

// MSPushPullLoss R5: R4 structure but with HARDWARE ds_add_f32 via
// unsafeAtomicAdd (plain atomicAdd on LDS floats compiles to a CAS loop --
// that was R1/R4's 240us). Per-lane-column bins [label][64]: no same-address
// collisions in a wave, fire-and-forget, no dependency chains.
// B=16, C=16, labels 0..16 (0 = background), seg = b*17+lab, NSEG=272.
// Scales (float4 vecs/batch): 2^18 / 2^16 / 2^14. Window = 1024 vecs.

#define NSEG 272
#define M_VAR 0.1f
#define TWO_M_DIST 3.0f
#define GRID_BLOCKS 1008   // scale0: 16*48, scale1: 16*12, scale2: 16*3

__device__ __forceinline__ void gatomic_add(float* p, float v) {
  __hip_atomic_fetch_add(p, v, __ATOMIC_RELAXED, __HIP_MEMORY_SCOPE_AGENT);
}

__device__ __forceinline__ void lds_fadd(float* p, float v) {
  unsafeAtomicAdd(p, v);   // -> ds_add_f32 (no return, no CAS loop)
}

struct Sel { const float4* f; const int4* g; int w, wend, wstride, scale, batch; };

__device__ __forceinline__ Sel pick(
    int b,
    const float4* f0, const int4* g0,
    const float4* f1, const int4* g1,
    const float4* f2, const int4* g2) {
  Sel s;
  if (b < 768) {
    int batch = b / 48, sub = b - batch * 48;
    s.f = f0; s.g = g0; s.scale = 0; s.batch = batch;
    int base = batch * 262144;
    s.w = base + sub * 1024; s.wend = base + 262144; s.wstride = 48 * 1024;
  } else if (b < 960) {
    int lb = b - 768, batch = lb / 12, sub = lb - batch * 12;
    s.f = f1; s.g = g1; s.scale = 1; s.batch = batch;
    int base = batch * 65536;
    s.w = base + sub * 1024; s.wend = base + 65536; s.wstride = 12 * 1024;
  } else {
    int lb = b - 960, batch = lb / 3, sub = lb - batch * 3;
    s.f = f2; s.g = g2; s.scale = 2; s.batch = batch;
    int base = batch * 16384;
    s.w = base + sub * 1024; s.wend = base + 16384; s.wstride = 3 * 1024;
  }
  return s;
}

// ---------------- pass 1: per-(batch,label) sums + per-(scale,batch,label) counts ----------------
__global__ __launch_bounds__(256) void pass1_kernel(
    const float4* __restrict__ f0, const int4* __restrict__ g0,
    const float4* __restrict__ f1, const int4* __restrict__ g1,
    const float4* __restrict__ f2, const int4* __restrict__ g2,
    float* __restrict__ tot_sum,   // [NSEG]
    float* __restrict__ cnt)       // [3][NSEG]
{
  __shared__ float sbin[17 * 64];  // [label][lane] sums   (4352 B)
  __shared__ float cbin[17 * 64];  // [label][lane] counts (4352 B)
  const int t = threadIdx.x;
  const int lane = t & 63;
  for (int i = t; i < 17 * 64; i += 256) { sbin[i] = 0.f; cbin[i] = 0.f; }
  __syncthreads();

  Sel s = pick(blockIdx.x, f0, g0, f1, g1, f2, g2);

  auto acc = [&](float f, int g) {
    unsigned l = (unsigned)g; l = l > 16u ? 16u : l;   // labels are 0..16; bin 0 never read
    int idx = (int)(l << 6) + lane;                    // bank = lane%32, 2-way aliasing
    lds_fadd(&sbin[idx], f);
    lds_fadd(&cbin[idx], 1.f);
  };

  for (int w = s.w; w < s.wend; w += s.wstride) {
    float4 F[4]; int4 G[4];
    #pragma unroll
    for (int j = 0; j < 4; ++j) { F[j] = s.f[w + j * 256 + t]; G[j] = s.g[w + j * 256 + t]; }
    #pragma unroll
    for (int j = 0; j < 4; ++j) {
      acc(F[j].x, G[j].x); acc(F[j].y, G[j].y); acc(F[j].z, G[j].z); acc(F[j].w, G[j].w);
    }
  }

  // reduce columns: [17][64] -> [17][1]
  for (int sh = 5; sh >= 0; --sh) {
    __syncthreads();
    int off = 1 << sh;
    for (int i = t; i < 17 * off; i += 256) {
      int l = i >> sh, c = i & (off - 1);
      sbin[l * 64 + c] += sbin[l * 64 + c + off];
      cbin[l * 64 + c] += cbin[l * 64 + c + off];
    }
  }
  __syncthreads();

  if (t < 16) {
    float sv = sbin[(t + 1) * 64];
    float cv = cbin[(t + 1) * 64];
    if (cv != 0.f) {
      gatomic_add(&tot_sum[s.batch * 17 + t + 1], sv);
      gatomic_add(&cnt[s.scale * NSEG + s.batch * 17 + t + 1], cv);
    }
  }
}

// ---------------- pass 2: inline mean, pull sums, last-block finalize ----------------
__global__ __launch_bounds__(256) void pass2_kernel(
    const float4* __restrict__ f0, const int4* __restrict__ g0,
    const float4* __restrict__ f1, const int4* __restrict__ g1,
    const float4* __restrict__ f2, const int4* __restrict__ g2,
    const float* __restrict__ tot_sum,  // [NSEG]
    const float* __restrict__ cnt,      // [3][NSEG]
    float* __restrict__ pull,           // [3][NSEG]
    int* __restrict__ counter,
    float* __restrict__ out)
{
  __shared__ float bin[17 * 64];   // [label][lane] pull sums
  __shared__ float s_mean[17];
  const int t = threadIdx.x;
  const int lane = t & 63;

  Sel s = pick(blockIdx.x, f0, g0, f1, g1, f2, g2);

  for (int i = t; i < 17 * 64; i += 256) bin[i] = 0.f;
  if (t < 17) {
    int seg = s.batch * 17 + t;
    float c = cnt[seg] + cnt[NSEG + seg] + cnt[2 * NSEG + seg];
    s_mean[t] = tot_sum[seg] / fmaxf(c, 1.f);
  }
  __syncthreads();

  auto acc = [&](float f, int g) {
    unsigned l = (unsigned)g; l = l > 16u ? 16u : l;    // bin 0 garbage, never read
    float d = fmaxf(fabsf(f - s_mean[l]) - M_VAR, 0.f); // same-address LDS reads broadcast
    lds_fadd(&bin[(int)(l << 6) + lane], d * d);
  };

  for (int w = s.w; w < s.wend; w += s.wstride) {
    float4 F[4]; int4 G[4];
    #pragma unroll
    for (int j = 0; j < 4; ++j) { F[j] = s.f[w + j * 256 + t]; G[j] = s.g[w + j * 256 + t]; }
    #pragma unroll
    for (int j = 0; j < 4; ++j) {
      acc(F[j].x, G[j].x); acc(F[j].y, G[j].y); acc(F[j].z, G[j].z); acc(F[j].w, G[j].w);
    }
  }

  for (int sh = 5; sh >= 0; --sh) {
    __syncthreads();
    int off = 1 << sh;
    for (int i = t; i < 17 * off; i += 256) {
      int l = i >> sh, c = i & (off - 1);
      bin[l * 64 + c] += bin[l * 64 + c + off];
    }
  }
  __syncthreads();

  if (t < 16) {
    float sv = bin[(t + 1) * 64];
    if (sv != 0.f) gatomic_add(&pull[s.scale * NSEG + s.batch * 17 + t + 1], sv);
  }

  // ---- completion ticket; last block finalizes ----
  __threadfence();
  __shared__ int is_last;
  if (t == 0) {
    int ticket = __hip_atomic_fetch_add(counter, 1, __ATOMIC_ACQ_REL, __HIP_MEMORY_SCOPE_AGENT);
    is_last = (ticket == GRID_BLOCKS - 1) ? 1 : 0;
  }
  __syncthreads();
  if (!is_last) return;
  __threadfence();

  __shared__ float fz_mean[NSEG];
  __shared__ unsigned char fz_pres[NSEG];
  for (int i = t; i < NSEG; i += 256) {
    float c = cnt[i] + cnt[NSEG + i] + cnt[2 * NSEG + i];
    fz_pres[i] = (c > 0.f) ? 1 : 0;
    fz_mean[i] = tot_sum[i] / fmaxf(c, 1.f);
  }
  __syncthreads();

  float pull_v = 0.f, pull_n = 0.f, push_v = 0.f, push_n = 0.f;

  for (int i = t; i < NSEG; i += 256) {
    int lab = i - (i / 17) * 17;
    if (lab >= 1 && fz_pres[i]) {
      float ps = 0.f;
      float c0 = cnt[i];            if (c0 > 0.f) ps += pull[i] / c0;
      float c1 = cnt[NSEG + i];     if (c1 > 0.f) ps += pull[NSEG + i] / c1;
      float c2 = cnt[2 * NSEG + i]; if (c2 > 0.f) ps += pull[2 * NSEG + i] / c2;
      pull_v += ps;
      pull_n += 1.f;
    }
  }
  {
    int b = t >> 4, ii = t & 15;
    int si = b * 17 + ii + 1;
    if (fz_pres[si]) {
      float mi = fz_mean[si];
      for (int j = 0; j < 16; ++j) {
        if (j == ii) continue;
        int sj = b * 17 + j + 1;
        if (fz_pres[sj]) {
          float d = fmaxf(TWO_M_DIST - fabsf(mi - fz_mean[sj]), 0.f);
          push_v += d * d;
          push_n += 1.f;
        }
      }
    }
  }

  #pragma unroll
  for (int o = 32; o > 0; o >>= 1) {
    pull_v += __shfl_down(pull_v, o);
    pull_n += __shfl_down(pull_n, o);
    push_v += __shfl_down(push_v, o);
    push_n += __shfl_down(push_n, o);
  }
  __shared__ float r[4][4];
  int wave = t >> 6;
  if ((t & 63) == 0) { r[wave][0] = pull_v; r[wave][1] = pull_n; r[wave][2] = push_v; r[wave][3] = push_n; }
  __syncthreads();
  if (t == 0) {
    float PV = 0, PN = 0, SV = 0, SN = 0;
    for (int w = 0; w < 4; ++w) { PV += r[w][0]; PN += r[w][1]; SV += r[w][2]; SN += r[w][3]; }
    out[0] = PV / fmaxf(PN, 1.f) + SV / fmaxf(SN, 1.f);
  }
}

extern "C" void kernel_launch(void* const* d_in, const int* in_sizes, int n_in,
                              void* d_out, int out_size, void* d_ws, size_t ws_size,
                              hipStream_t stream) {
  // setup_inputs() dict order: featmap0, gt0, featmap1, gt1, featmap2, gt2
  const float4* f0 = (const float4*)d_in[0];
  const int4*   g0 = (const int4*)  d_in[1];
  const float4* f1 = (const float4*)d_in[2];
  const int4*   g1 = (const int4*)  d_in[3];
  const float4* f2 = (const float4*)d_in[4];
  const int4*   g2 = (const int4*)  d_in[5];

  float* ws      = (float*)d_ws;
  float* tot_sum = ws;                 // [NSEG]
  float* cnt     = ws + NSEG;          // [3][NSEG]
  float* pull    = ws + 4 * NSEG;      // [3][NSEG]
  int*   counter = (int*)(ws + 7 * NSEG);

  hipMemsetAsync(d_ws, 0, (7 * NSEG + 1) * sizeof(float), stream);
  pass1_kernel<<<GRID_BLOCKS, 256, 0, stream>>>(f0, g0, f1, g1, f2, g2, tot_sum, cnt);
  pass2_kernel<<<GRID_BLOCKS, 256, 0, stream>>>(f0, g0, f1, g1, f2, g2, tot_sum, cnt,
                                                pull, counter, (float*)d_out);
}

// Round 6
// 326.348 us; speedup vs baseline: 1.7721x; 1.7721x over previous
//
#include <hip/hip_runtime.h>

// MSPushPullLoss R6: per-WAVE LDS bins [17][64], plain b32 read/add/write with
// column-offset scheme guaranteeing distinct addresses within each batched
// group (slot k -> column (lane+8k)&63). Reads batched before writes; no
// atomics, no CAS, 2-way bank aliasing only (free). Counts at +4352B offset.
// Pricing: ~4 clean b32 ops/elem -> ~13us LDS/CU << 28.7us memory floor.
// B=16, C=16, labels 0..16 (0 = background), seg = b*17+lab, NSEG=272.

#define NSEG 272
#define M_VAR 0.1f
#define TWO_M_DIST 3.0f
#define GRID_BLOCKS 1008   // scale0 16*48, scale1 16*12, scale2 16*3 -> 10.67 windows each

__device__ __forceinline__ void gatomic_add(float* p, float v) {
  __hip_atomic_fetch_add(p, v, __ATOMIC_RELAXED, __HIP_MEMORY_SCOPE_AGENT);
}

struct Sel { const float4* f; const int4* g; int w, wend, stride, scale, batch; };

// Window = 512 vecs (2 float4/thread). All blocks get ~10.67 windows (balanced).
__device__ __forceinline__ Sel pick(
    int b,
    const float4* f0, const int4* g0,
    const float4* f1, const int4* g1,
    const float4* f2, const int4* g2) {
  Sel s;
  if (b < 768) {
    int batch = b / 48, sub = b - batch * 48;
    s.f = f0; s.g = g0; s.scale = 0; s.batch = batch;
    s.w = batch * 262144 + sub * 512; s.wend = (batch + 1) * 262144; s.stride = 48 * 512;
  } else if (b < 960) {
    int lb = b - 768, batch = lb / 12, sub = lb - batch * 12;
    s.f = f1; s.g = g1; s.scale = 1; s.batch = batch;
    s.w = batch * 65536 + sub * 512; s.wend = (batch + 1) * 65536; s.stride = 12 * 512;
  } else {
    int lb = b - 960, batch = lb / 3, sub = lb - batch * 3;
    s.f = f2; s.g = g2; s.scale = 2; s.batch = batch;
    s.w = batch * 16384 + sub * 512; s.wend = (batch + 1) * 16384; s.stride = 3 * 512;
  }
  return s;
}

// ---------------- pass 1: per-(batch,label) sums + per-(scale,batch,label) counts ----------------
__global__ __launch_bounds__(256) void pass1_kernel(
    const float4* __restrict__ f0, const int4* __restrict__ g0,
    const float4* __restrict__ f1, const int4* __restrict__ g1,
    const float4* __restrict__ f2, const int4* __restrict__ g2,
    float* __restrict__ tot_sum,   // [NSEG]
    float* __restrict__ cnt)       // [3][NSEG]
{
  // bins[wave][0]=sums[17][64], bins[wave][1]=counts[17][64]  (34816 B total)
  __shared__ float bins[4][2][17 * 64];
  const int t = threadIdx.x, lane = t & 63, wave = t >> 6;
  float* SB = &bins[wave][0][0];
  float* CB = &bins[wave][1][0];
  float* P0 = &bins[0][0][0];
  for (int i = t; i < 4 * 2 * 17 * 64; i += 256) P0[i] = 0.f;
  __syncthreads();

  Sel s = pick(blockIdx.x, f0, g0, f1, g1, f2, g2);

  int w = s.w;
  float4 FA = s.f[w + t],       FB = s.f[w + 256 + t];
  int4   GA = s.g[w + t],       GB = s.g[w + 256 + t];
  while (true) {
    int wn = w + s.stride;
    bool hn = wn < s.wend;
    float4 FA2, FB2; int4 GA2, GB2;
    if (hn) { FA2 = s.f[wn + t]; FB2 = s.f[wn + 256 + t];
              GA2 = s.g[wn + t]; GB2 = s.g[wn + 256 + t]; }

    // 8 elements, 8 provably-distinct columns (offsets 0,8,...,56 mod 64)
    int idx[8];
    idx[0] = (GA.x << 6) + ( lane        & 63);
    idx[1] = (GA.y << 6) + ((lane +  8) & 63);
    idx[2] = (GA.z << 6) + ((lane + 16) & 63);
    idx[3] = (GA.w << 6) + ((lane + 24) & 63);
    idx[4] = (GB.x << 6) + ((lane + 32) & 63);
    idx[5] = (GB.y << 6) + ((lane + 40) & 63);
    idx[6] = (GB.z << 6) + ((lane + 48) & 63);
    idx[7] = (GB.w << 6) + ((lane + 56) & 63);
    float fs[8] = {FA.x, FA.y, FA.z, FA.w, FB.x, FB.y, FB.z, FB.w};

    float os[8], oc[8];
    #pragma unroll
    for (int k = 0; k < 8; ++k) { os[k] = SB[idx[k]]; oc[k] = CB[idx[k]]; }
    #pragma unroll
    for (int k = 0; k < 8; ++k) { SB[idx[k]] = os[k] + fs[k]; CB[idx[k]] = oc[k] + 1.f; }

    if (!hn) break;
    FA = FA2; FB = FB2; GA = GA2; GB = GB2; w = wn;
  }
  __syncthreads();

  // fold 4 waves: P0[i] += P0[i + w*2176]
  for (int i = t; i < 2 * 17 * 64; i += 256)
    P0[i] = P0[i] + P0[i + 2176] + P0[i + 2 * 2176] + P0[i + 3 * 2176];

  // tree-reduce 64 columns over 34 rows (17 sum rows + 17 cnt rows)
  for (int sh = 5; sh >= 0; --sh) {
    __syncthreads();
    int off = 1 << sh;
    for (int i = t; i < 34 * off; i += 256) {
      int r = i >> sh, c = i & (off - 1);
      P0[r * 64 + c] += P0[r * 64 + c + off];
    }
  }
  __syncthreads();

  if (t < 16) {
    float sv = P0[(t + 1) * 64];
    float cv = P0[(17 + t + 1) * 64];
    if (cv != 0.f) {
      gatomic_add(&tot_sum[s.batch * 17 + t + 1], sv);
      gatomic_add(&cnt[s.scale * NSEG + s.batch * 17 + t + 1], cv);
    }
  }
}

// ---------------- pass 2: inline mean, pull sums, last-block finalize ----------------
__global__ __launch_bounds__(256) void pass2_kernel(
    const float4* __restrict__ f0, const int4* __restrict__ g0,
    const float4* __restrict__ f1, const int4* __restrict__ g1,
    const float4* __restrict__ f2, const int4* __restrict__ g2,
    const float* __restrict__ tot_sum,  // [NSEG]
    const float* __restrict__ cnt,      // [3][NSEG]
    float* __restrict__ pull,           // [3][NSEG]
    int* __restrict__ counter,
    float* __restrict__ out)
{
  __shared__ float bins[4][17 * 64];   // per-wave pull bins (17408 B)
  __shared__ float meanR[17 * 64];     // mean replicated 64x: bank-clean gather
  const int t = threadIdx.x, lane = t & 63, wave = t >> 6;
  float* SB = &bins[wave][0];
  float* P0 = &bins[0][0];

  Sel s = pick(blockIdx.x, f0, g0, f1, g1, f2, g2);

  for (int i = t; i < 4 * 17 * 64; i += 256) P0[i] = 0.f;
  for (int i = t; i < 17 * 64; i += 256) {
    int l = i >> 6, seg = s.batch * 17 + l;
    float c = cnt[seg] + cnt[NSEG + seg] + cnt[2 * NSEG + seg];
    meanR[i] = tot_sum[seg] / fmaxf(c, 1.f);
  }
  __syncthreads();

  int w = s.w;
  float4 FA = s.f[w + t],       FB = s.f[w + 256 + t];
  int4   GA = s.g[w + t],       GB = s.g[w + 256 + t];
  while (true) {
    int wn = w + s.stride;
    bool hn = wn < s.wend;
    float4 FA2, FB2; int4 GA2, GB2;
    if (hn) { FA2 = s.f[wn + t]; FB2 = s.f[wn + 256 + t];
              GA2 = s.g[wn + t]; GB2 = s.g[wn + 256 + t]; }

    int idx[8];
    idx[0] = (GA.x << 6) + ( lane        & 63);
    idx[1] = (GA.y << 6) + ((lane +  8) & 63);
    idx[2] = (GA.z << 6) + ((lane + 16) & 63);
    idx[3] = (GA.w << 6) + ((lane + 24) & 63);
    idx[4] = (GB.x << 6) + ((lane + 32) & 63);
    idx[5] = (GB.y << 6) + ((lane + 40) & 63);
    idx[6] = (GB.z << 6) + ((lane + 48) & 63);
    idx[7] = (GB.w << 6) + ((lane + 56) & 63);
    int gi[8] = {GA.x, GA.y, GA.z, GA.w, GB.x, GB.y, GB.z, GB.w};
    float fs[8] = {FA.x, FA.y, FA.z, FA.w, FB.x, FB.y, FB.z, FB.w};

    float mv[8], os[8];
    #pragma unroll
    for (int k = 0; k < 8; ++k) mv[k] = meanR[(gi[k] << 6) + lane];  // bank = lane%32, clean
    #pragma unroll
    for (int k = 0; k < 8; ++k) os[k] = SB[idx[k]];
    #pragma unroll
    for (int k = 0; k < 8; ++k) {
      float d = fmaxf(fabsf(fs[k] - mv[k]) - M_VAR, 0.f);
      SB[idx[k]] = os[k] + d * d;       // label 0 accumulates garbage, never read
    }

    if (!hn) break;
    FA = FA2; FB = FB2; GA = GA2; GB = GB2; w = wn;
  }
  __syncthreads();

  for (int i = t; i < 17 * 64; i += 256)
    P0[i] = P0[i] + P0[i + 1088] + P0[i + 2 * 1088] + P0[i + 3 * 1088];
  for (int sh = 5; sh >= 0; --sh) {
    __syncthreads();
    int off = 1 << sh;
    for (int i = t; i < 17 * off; i += 256) {
      int r = i >> sh, c = i & (off - 1);
      P0[r * 64 + c] += P0[r * 64 + c + off];
    }
  }
  __syncthreads();

  if (t < 16) {
    float sv = P0[(t + 1) * 64];
    if (sv != 0.f) gatomic_add(&pull[s.scale * NSEG + s.batch * 17 + t + 1], sv);
  }

  // ---- completion ticket; last block finalizes ----
  __threadfence();
  __shared__ int is_last;
  if (t == 0) {
    int ticket = __hip_atomic_fetch_add(counter, 1, __ATOMIC_ACQ_REL, __HIP_MEMORY_SCOPE_AGENT);
    is_last = (ticket == GRID_BLOCKS - 1) ? 1 : 0;
  }
  __syncthreads();
  if (!is_last) return;
  __threadfence();

  __shared__ float fz_mean[NSEG];
  __shared__ unsigned char fz_pres[NSEG];
  for (int i = t; i < NSEG; i += 256) {
    float c = cnt[i] + cnt[NSEG + i] + cnt[2 * NSEG + i];
    fz_pres[i] = (c > 0.f) ? 1 : 0;
    fz_mean[i] = tot_sum[i] / fmaxf(c, 1.f);
  }
  __syncthreads();

  float pull_v = 0.f, pull_n = 0.f, push_v = 0.f, push_n = 0.f;

  for (int i = t; i < NSEG; i += 256) {
    int lab = i - (i / 17) * 17;
    if (lab >= 1 && fz_pres[i]) {
      float ps = 0.f;
      float c0 = cnt[i];            if (c0 > 0.f) ps += pull[i] / c0;
      float c1 = cnt[NSEG + i];     if (c1 > 0.f) ps += pull[NSEG + i] / c1;
      float c2 = cnt[2 * NSEG + i]; if (c2 > 0.f) ps += pull[2 * NSEG + i] / c2;
      pull_v += ps;
      pull_n += 1.f;
    }
  }
  {
    int b = t >> 4, ii = t & 15;
    int si = b * 17 + ii + 1;
    if (fz_pres[si]) {
      float mi = fz_mean[si];
      for (int j = 0; j < 16; ++j) {
        if (j == ii) continue;
        int sj = b * 17 + j + 1;
        if (fz_pres[sj]) {
          float d = fmaxf(TWO_M_DIST - fabsf(mi - fz_mean[sj]), 0.f);
          push_v += d * d;
          push_n += 1.f;
        }
      }
    }
  }

  #pragma unroll
  for (int o = 32; o > 0; o >>= 1) {
    pull_v += __shfl_down(pull_v, o);
    pull_n += __shfl_down(pull_n, o);
    push_v += __shfl_down(push_v, o);
    push_n += __shfl_down(push_n, o);
  }
  __shared__ float r[4][4];
  if ((t & 63) == 0) { r[wave][0] = pull_v; r[wave][1] = pull_n; r[wave][2] = push_v; r[wave][3] = push_n; }
  __syncthreads();
  if (t == 0) {
    float PV = 0, PN = 0, SV = 0, SN = 0;
    for (int wv = 0; wv < 4; ++wv) { PV += r[wv][0]; PN += r[wv][1]; SV += r[wv][2]; SN += r[wv][3]; }
    out[0] = PV / fmaxf(PN, 1.f) + SV / fmaxf(SN, 1.f);
  }
}

extern "C" void kernel_launch(void* const* d_in, const int* in_sizes, int n_in,
                              void* d_out, int out_size, void* d_ws, size_t ws_size,
                              hipStream_t stream) {
  // setup_inputs() dict order: featmap0, gt0, featmap1, gt1, featmap2, gt2
  const float4* f0 = (const float4*)d_in[0];
  const int4*   g0 = (const int4*)  d_in[1];
  const float4* f1 = (const float4*)d_in[2];
  const int4*   g1 = (const int4*)  d_in[3];
  const float4* f2 = (const float4*)d_in[4];
  const int4*   g2 = (const int4*)  d_in[5];

  float* ws      = (float*)d_ws;
  float* tot_sum = ws;                 // [NSEG]
  float* cnt     = ws + NSEG;          // [3][NSEG]
  float* pull    = ws + 4 * NSEG;      // [3][NSEG]
  int*   counter = (int*)(ws + 7 * NSEG);

  hipMemsetAsync(d_ws, 0, (7 * NSEG + 1) * sizeof(float), stream);
  pass1_kernel<<<GRID_BLOCKS, 256, 0, stream>>>(f0, g0, f1, g1, f2, g2, tot_sum, cnt);
  pass2_kernel<<<GRID_BLOCKS, 256, 0, stream>>>(f0, g0, f1, g1, f2, g2, tot_sum, cnt,
                                                pull, counter, (float*)d_out);
}